// Round 4
// baseline (15568.256 us; speedup 1.0000x reference)
//
#include <hip/hip_runtime.h>
#include <stdint.h>
#include <math.h>

#define SEQ   256
#define BATCH 8
#define HID   1024
#define VOCAB 32000

typedef __attribute__((ext_vector_type(8))) short s16x8;
typedef __attribute__((ext_vector_type(4))) float f32x4;

__device__ __forceinline__ unsigned short f2bf(float f) {
    union { float f; uint32_t u; } v; v.f = f;
    uint32_t r = v.u + 0x7fffu + ((v.u >> 16) & 1u);   // RNE
    return (unsigned short)(r >> 16);
}
__device__ __forceinline__ float bf2f(unsigned short h) {
    union { float f; uint32_t u; } v; v.u = ((uint32_t)h) << 16;
    return v.f;
}

// ---------------- embedding gather: x[row] = emb[idx[row]] ----------------
__global__ __launch_bounds__(256)
void k_embed(const int* __restrict__ idx, const float* __restrict__ emb,
             float* __restrict__ x) {
    const int row = blockIdx.x;                  // b*SEQ + s
    const int id  = idx[row];
    const f32x4 v = *(const f32x4*)(emb + (size_t)id*HID + threadIdx.x*4);
    *(f32x4*)(x + (size_t)row*HID + threadIdx.x*4) = v;
}

// ---------------- f32 -> bf16 hi/lo split ----------------
__global__ __launch_bounds__(256)
void k_cvt(const float* __restrict__ in, unsigned short* __restrict__ hi,
           unsigned short* __restrict__ lo, int n) {
    for (int i = blockIdx.x*blockDim.x + threadIdx.x; i < n; i += gridDim.x*blockDim.x) {
        float f = in[i];
        unsigned short h = f2bf(f);
        hi[i] = h;
        lo[i] = f2bf(f - bf2f(h));
    }
}

// ---------------- f64 GEMM: C[M][N](f64) = A[M][K](f32) @ B[N][K]^T(f32) ----------------
// M,N mult of 64; K mult of 32. 256 thr, thread-tile 4x4.
__global__ __launch_bounds__(256)
void k_gemm_f64(const float* __restrict__ A, const float* __restrict__ B,
                double* __restrict__ C, int M, int N, int K) {
    __shared__ float As[64][33];
    __shared__ float Bs[64][33];
    const int nbn = N >> 6;
    const int bm = blockIdx.x / nbn, bn = blockIdx.x % nbn;
    const int tid = threadIdx.x;
    const int tr = tid >> 4, tc = tid & 15;          // 16x16 thread grid
    const int lr = tid >> 2, lc = (tid & 3) << 3;    // loader: row, col(0/8/16/24)
    double acc[4][4];
    #pragma unroll
    for (int r = 0; r < 4; ++r)
        #pragma unroll
        for (int c = 0; c < 4; ++c) acc[r][c] = 0.0;
    const float* Ag = A + (size_t)(bm*64 + lr)*K + lc;
    const float* Bg = B + (size_t)(bn*64 + lr)*K + lc;
    for (int k0 = 0; k0 < K; k0 += 32) {
        f32x4 a0 = *(const f32x4*)(Ag + k0);
        f32x4 a1 = *(const f32x4*)(Ag + k0 + 4);
        f32x4 b0 = *(const f32x4*)(Bg + k0);
        f32x4 b1 = *(const f32x4*)(Bg + k0 + 4);
        __syncthreads();
        #pragma unroll
        for (int e = 0; e < 4; ++e) {
            As[lr][lc + e]     = a0[e];
            As[lr][lc + 4 + e] = a1[e];
            Bs[lr][lc + e]     = b0[e];
            Bs[lr][lc + 4 + e] = b1[e];
        }
        __syncthreads();
        #pragma unroll
        for (int kk = 0; kk < 32; ++kk) {
            double ad[4], bd[4];
            #pragma unroll
            for (int r = 0; r < 4; ++r) ad[r] = (double)As[tr*4 + r][kk];
            #pragma unroll
            for (int c = 0; c < 4; ++c) bd[c] = (double)Bs[tc*4 + c][kk];
            #pragma unroll
            for (int r = 0; r < 4; ++r)
                #pragma unroll
                for (int c = 0; c < 4; ++c)
                    acc[r][c] = fma(ad[r], bd[c], acc[r][c]);
        }
    }
    #pragma unroll
    for (int r = 0; r < 4; ++r) {
        double* Cr = C + (size_t)(bm*64 + tr*4 + r)*N + bn*64 + tc*4;
        #pragma unroll
        for (int c = 0; c < 4; ++c) Cr[c] = acc[r][c];
    }
}

// ------- split-bf16 MFMA GEMM: C = Ahi@Bhi^T + Ahi@Blo^T + Alo@Bhi^T (+bias) -------
// Used only for the (unamplified) vocab projection. M,N mult of 128; K mult of 32.
__global__ __launch_bounds__(256)
void k_gemm3(const unsigned short* __restrict__ Ahi,
             const unsigned short* __restrict__ Alo,
             const unsigned short* __restrict__ Bhi,
             const unsigned short* __restrict__ Blo,
             float* __restrict__ C,
             const float* __restrict__ bias,
             int M, int N, int K) {
    __shared__ unsigned short Ash[128][32];
    __shared__ unsigned short Asl[128][32];
    __shared__ unsigned short Bsh[128][32];
    __shared__ unsigned short Bsl[128][32];
    const int nbn = N >> 7;
    const int bm = blockIdx.x / nbn, bn = blockIdx.x % nbn;
    const int tid = threadIdx.x;
    const int lane = tid & 63, wave = tid >> 6;
    const int wr = wave >> 1, wc = wave & 1;
    const int lrow = tid >> 2, lcol = (tid & 3) << 3;
    const size_t aoff = (size_t)(bm*128 + lrow)*K + lcol;
    const size_t boff = (size_t)(bn*128 + lrow)*K + lcol;
    const int frow = lane & 15, fk = (lane >> 4) << 3;

    f32x4 acc[4][4];
    #pragma unroll
    for (int i = 0; i < 4; ++i)
        #pragma unroll
        for (int j = 0; j < 4; ++j)
            #pragma unroll
            for (int e = 0; e < 4; ++e) acc[i][j][e] = 0.f;

    for (int k0 = 0; k0 < K; k0 += 32) {
        uint4 ah0 = *(const uint4*)(Ahi + aoff + k0);
        uint4 ah1 = *(const uint4*)(Ahi + aoff + (size_t)64*K + k0);
        uint4 al0 = *(const uint4*)(Alo + aoff + k0);
        uint4 al1 = *(const uint4*)(Alo + aoff + (size_t)64*K + k0);
        uint4 bh0 = *(const uint4*)(Bhi + boff + k0);
        uint4 bh1 = *(const uint4*)(Bhi + boff + (size_t)64*K + k0);
        uint4 bl0 = *(const uint4*)(Blo + boff + k0);
        uint4 bl1 = *(const uint4*)(Blo + boff + (size_t)64*K + k0);
        __syncthreads();
        *(uint4*)&Ash[lrow][lcol]      = ah0;
        *(uint4*)&Ash[lrow + 64][lcol] = ah1;
        *(uint4*)&Asl[lrow][lcol]      = al0;
        *(uint4*)&Asl[lrow + 64][lcol] = al1;
        *(uint4*)&Bsh[lrow][lcol]      = bh0;
        *(uint4*)&Bsh[lrow + 64][lcol] = bh1;
        *(uint4*)&Bsl[lrow][lcol]      = bl0;
        *(uint4*)&Bsl[lrow + 64][lcol] = bl1;
        __syncthreads();
        s16x8 ah[4], al[4], bh[4], bl[4];
        #pragma unroll
        for (int mi = 0; mi < 4; ++mi) {
            ah[mi] = *(const s16x8*)&Ash[wr*64 + mi*16 + frow][fk];
            al[mi] = *(const s16x8*)&Asl[wr*64 + mi*16 + frow][fk];
        }
        #pragma unroll
        for (int ni = 0; ni < 4; ++ni) {
            bh[ni] = *(const s16x8*)&Bsh[wc*64 + ni*16 + frow][fk];
            bl[ni] = *(const s16x8*)&Bsl[wc*64 + ni*16 + frow][fk];
        }
        #pragma unroll
        for (int mi = 0; mi < 4; ++mi)
            #pragma unroll
            for (int ni = 0; ni < 4; ++ni) {
                acc[mi][ni] = __builtin_amdgcn_mfma_f32_16x16x32_bf16(ah[mi], bh[ni], acc[mi][ni], 0, 0, 0);
                acc[mi][ni] = __builtin_amdgcn_mfma_f32_16x16x32_bf16(ah[mi], bl[ni], acc[mi][ni], 0, 0, 0);
                acc[mi][ni] = __builtin_amdgcn_mfma_f32_16x16x32_bf16(al[mi], bh[ni], acc[mi][ni], 0, 0, 0);
            }
    }

    #pragma unroll
    for (int mi = 0; mi < 4; ++mi) {
        const int row0 = bm*128 + wr*64 + mi*16 + ((lane >> 4) << 2);
        #pragma unroll
        for (int ni = 0; ni < 4; ++ni) {
            const int col = bn*128 + wc*64 + ni*16 + (lane & 15);
            const float bv = bias ? bias[col] : 0.f;
            #pragma unroll
            for (int r = 0; r < 4; ++r) {
                const size_t ix = (size_t)(row0 + r)*N + col;
                C[ix] = acc[mi][ni][r] + bv;
            }
        }
    }
}

// ---------------- sLSTM scan tick, f64 math (skewed: layer0 t=k || layer1 t=k-1) --------
// Grid: 512 WGs x 256 thr. WG<256: layer0 (4 units, 1/wave). WG>=256: layer1.
// h stored f32 (double-buffered by parity); c stored f64; gates accumulated f64.
__global__ __launch_bounds__(256)
void k_scan(const float* __restrict__ whh0,
            const float* __restrict__ wih1,
            const float* __restrict__ whh1,
            const float* __restrict__ bias0,
            const float* __restrict__ bias1,
            const double* __restrict__ G0,     // [B*SEQ][4096] f64 = x @ w_ih0^T
            float* h0, double* c0, float* h1, double* c1,
            float* __restrict__ y,             // [B*SEQ][HID] f32
            int k) {
    const int wgid = blockIdx.x;
    const int wave = threadIdx.x >> 6;
    const int lane = threadIdx.x & 63;
    const int HB = BATCH * HID;

    if (wgid < 256) {                          // ---- layer 0, t = k ----
        if (k >= SEQ) return;
        const int t = k;
        const int u = wgid*4 + wave;
        const float* hp = h0 + ((k + 1) & 1) * HB;   // h0(t-1)
        double acc[4][8];
        #pragma unroll
        for (int g = 0; g < 4; ++g)
            #pragma unroll
            for (int b = 0; b < 8; ++b) acc[g][b] = 0.0;
        #pragma unroll
        for (int jj = 0; jj < 4; ++jj) {
            const int kb = 4*lane + 256*jj;
            double hd[8][4];
            #pragma unroll
            for (int b = 0; b < 8; ++b) {
                const f32x4 hv = *(const f32x4*)(hp + b*HID + kb);
                #pragma unroll
                for (int e = 0; e < 4; ++e) hd[b][e] = (double)hv[e];
            }
            #pragma unroll
            for (int g = 0; g < 4; ++g) {
                const f32x4 wv = *(const f32x4*)(whh0 + (size_t)(g*HID + u)*HID + kb);
                double wd[4];
                #pragma unroll
                for (int e = 0; e < 4; ++e) wd[e] = (double)wv[e];
                #pragma unroll
                for (int b = 0; b < 8; ++b)
                    #pragma unroll
                    for (int e = 0; e < 4; ++e)
                        acc[g][b] = fma(wd[e], hd[b][e], acc[g][b]);
            }
        }
        #pragma unroll
        for (int g = 0; g < 4; ++g)
            #pragma unroll
            for (int b = 0; b < 8; ++b) {
                double v = acc[g][b];
                #pragma unroll
                for (int off = 32; off > 0; off >>= 1) v += __shfl_xor(v, off, 64);
                acc[g][b] = v;
            }
        if (lane < 8) {
            const int b = lane;
            const double* g0r = G0 + (size_t)(b*SEQ + t)*4096;
            const double gi = acc[0][b] + g0r[u]         + (double)bias0[u];
            const double gf = acc[1][b] + g0r[HID + u]   + (double)bias0[HID + u];
            const double gg = acc[2][b] + g0r[2*HID + u] + (double)bias0[2*HID + u];
            const double go = acc[3][b] + g0r[3*HID + u] + (double)bias0[3*HID + u];
            const double cc = exp(gf)*c0[b*HID + u] + exp(gi)*tanh(gg);
            const double hh = tanh(cc) / (1.0 + exp(-go));
            c0[b*HID + u] = cc;
            h0[(k & 1)*HB + b*HID + u] = (float)hh;
        }
    } else {                                   // ---- layer 1, t = k-1 ----
        if (k < 1) return;
        const int t = k - 1;
        const int u = (wgid - 256)*4 + wave;
        const float* hin = h0 + ((k + 1) & 1) * HB;  // h0(t)
        const float* hpp = h1 + (k & 1) * HB;        // h1(t-1)
        double acc[4][8];
        #pragma unroll
        for (int g = 0; g < 4; ++g)
            #pragma unroll
            for (int b = 0; b < 8; ++b) acc[g][b] = 0.0;
        #pragma unroll
        for (int jj = 0; jj < 4; ++jj) {
            const int kb = 4*lane + 256*jj;
            double hd[8][4];
            // pass 1: wih1 . h0(t)
            #pragma unroll
            for (int b = 0; b < 8; ++b) {
                const f32x4 hv = *(const f32x4*)(hin + b*HID + kb);
                #pragma unroll
                for (int e = 0; e < 4; ++e) hd[b][e] = (double)hv[e];
            }
            #pragma unroll
            for (int g = 0; g < 4; ++g) {
                const f32x4 wv = *(const f32x4*)(wih1 + (size_t)(g*HID + u)*HID + kb);
                double wd[4];
                #pragma unroll
                for (int e = 0; e < 4; ++e) wd[e] = (double)wv[e];
                #pragma unroll
                for (int b = 0; b < 8; ++b)
                    #pragma unroll
                    for (int e = 0; e < 4; ++e)
                        acc[g][b] = fma(wd[e], hd[b][e], acc[g][b]);
            }
            // pass 2: whh1 . h1(t-1)  (reuses hd)
            #pragma unroll
            for (int b = 0; b < 8; ++b) {
                const f32x4 hv = *(const f32x4*)(hpp + b*HID + kb);
                #pragma unroll
                for (int e = 0; e < 4; ++e) hd[b][e] = (double)hv[e];
            }
            #pragma unroll
            for (int g = 0; g < 4; ++g) {
                const f32x4 wv = *(const f32x4*)(whh1 + (size_t)(g*HID + u)*HID + kb);
                double wd[4];
                #pragma unroll
                for (int e = 0; e < 4; ++e) wd[e] = (double)wv[e];
                #pragma unroll
                for (int b = 0; b < 8; ++b)
                    #pragma unroll
                    for (int e = 0; e < 4; ++e)
                        acc[g][b] = fma(wd[e], hd[b][e], acc[g][b]);
            }
        }
        #pragma unroll
        for (int g = 0; g < 4; ++g)
            #pragma unroll
            for (int b = 0; b < 8; ++b) {
                double v = acc[g][b];
                #pragma unroll
                for (int off = 32; off > 0; off >>= 1) v += __shfl_xor(v, off, 64);
                acc[g][b] = v;
            }
        if (lane < 8) {
            const int b = lane;
            const double gi = acc[0][b] + (double)bias1[u];
            const double gf = acc[1][b] + (double)bias1[HID + u];
            const double gg = acc[2][b] + (double)bias1[2*HID + u];
            const double go = acc[3][b] + (double)bias1[3*HID + u];
            const double cc = exp(gf)*c1[b*HID + u] + exp(gi)*tanh(gg);
            const double hh = tanh(cc) / (1.0 + exp(-go));
            c1[b*HID + u] = cc;
            h1[((k + 1) & 1)*HB + b*HID + u] = (float)hh;
            y[(size_t)(b*SEQ + t)*HID + u] = (float)hh;
        }
    }
}

// ---------------- GELU(exact) + residual + LayerNorm, f64 internals ----------------
__global__ __launch_bounds__(256)
void k_post(const float* __restrict__ y, const float* __restrict__ xin,
            const float* __restrict__ gamma, const float* __restrict__ beta,
            float* __restrict__ xout) {
    const int row = blockIdx.x;
    const int tid = threadIdx.x;
    const f32x4 v  = *(const f32x4*)(y   + (size_t)row*HID + tid*4);
    const f32x4 xr = *(const f32x4*)(xin + (size_t)row*HID + tid*4);
    double o[4]; double s = 0.0, q = 0.0;
    #pragma unroll
    for (int e = 0; e < 4; ++e) {
        const double t  = (double)v[e];
        const double ge = 0.5 * t * (1.0 + erf(t * 0.7071067811865476));
        const double u  = ge + (double)xr[e];
        o[e] = u; s += u; q += u*u;
    }
    #pragma unroll
    for (int off = 32; off > 0; off >>= 1) {
        s += __shfl_xor(s, off, 64);
        q += __shfl_xor(q, off, 64);
    }
    __shared__ double rs[4], rq[4];
    const int wv = tid >> 6, lane = tid & 63;
    if (lane == 0) { rs[wv] = s; rq[wv] = q; }
    __syncthreads();
    s = rs[0] + rs[1] + rs[2] + rs[3];
    q = rq[0] + rq[1] + rq[2] + rq[3];
    const double mu   = s * (1.0/HID);
    const double var  = q * (1.0/HID) - mu*mu;
    const double rstd = 1.0 / sqrt(var + 1e-5);
    f32x4 ov;
    #pragma unroll
    for (int e = 0; e < 4; ++e) {
        const int col = tid*4 + e;
        ov[e] = (float)((o[e] - mu)*rstd*(double)gamma[col] + (double)beta[col]);
    }
    *(f32x4*)(xout + (size_t)row*HID + tid*4) = ov;
}

// -------------------------------------------------------------------------
extern "C" void kernel_launch(void* const* d_in, const int* in_sizes, int n_in,
                              void* d_out, int out_size, void* d_ws, size_t ws_size,
                              hipStream_t stream) {
    const int*   idx   = (const int*)d_in[0];
    const float* emb   = (const float*)d_in[1];
    const float* w_ih  = (const float*)d_in[2];
    const float* w_hh  = (const float*)d_in[3];
    const float* bias  = (const float*)d_in[4];
    const float* ln_g  = (const float*)d_in[5];
    const float* ln_b  = (const float*)d_in[6];
    const float* out_w = (const float*)d_in[7];
    const float* out_b = (const float*)d_in[8];
    float* logits = (float*)d_out;

    char* ws = (char*)d_ws;
    size_t off = 0;
    auto alloc = [&](size_t bytes) -> char* {
        char* p = ws + off;
        off = (off + bytes + 255) & ~(size_t)255;
        return p;
    };
    const int ROWS = BATCH * SEQ;                       // 2048
    float*          X    = (float*)         alloc((size_t)ROWS*HID*4);       //  8.39 MB
    unsigned short* XHI  = (unsigned short*)alloc((size_t)ROWS*HID*2);       //  4.19 MB
    unsigned short* XLO  = (unsigned short*)alloc((size_t)ROWS*HID*2);       //  4.19 MB
    char*           ST   =                  alloc(262144);                   //  0.26 MB
    // transient region: (G0 f64 + Y) during blocks, (OWHI + OWLO) for the final GEMM
    char*           REG  = alloc((size_t)VOCAB*HID*2*2);                     // 131.1 MB
    double*         G0p  = (double*)REG;                                     //  67.1 MB
    float*          Y    = (float*)(REG + (size_t)ROWS*4096*8);              //   8.39 MB
    unsigned short* OWHI = (unsigned short*)REG;                             //  65.5 MB
    unsigned short* OWLO = (unsigned short*)(REG + (size_t)VOCAB*HID*2);     //  65.5 MB

    float*  h0 = (float*)ST;                    // [2][8][1024] f32
    float*  h1 = (float*)(ST + 65536);          // [2][8][1024] f32
    double* c0 = (double*)(ST + 131072);        // [8][1024] f64
    double* c1 = (double*)(ST + 196608);        // [8][1024] f64

    k_embed<<<ROWS, 256, 0, stream>>>(idx, emb, X);

    for (int blk = 0; blk < 2; ++blk) {
        const float* wih_b = w_ih + (size_t)blk*2*4096*HID;
        const float* whh_b = w_hh + (size_t)blk*2*4096*HID;
        const float* b0 = bias + (size_t)blk*2*4096;
        const float* b1 = b0 + 4096;

        // G0 = x @ w_ih0^T in f64 (this feeds the chaotic recurrence)
        k_gemm_f64<<<(ROWS/64)*(4096/64), 256, 0, stream>>>(X, wih_b, G0p,
                                                            ROWS, 4096, HID);

        hipMemsetAsync(ST, 0, 262144, stream);          // zero h0/h1/c0/c1

        const float* whh0 = whh_b;
        const float* wih1 = wih_b + (size_t)4096*HID;
        const float* whh1 = whh_b + (size_t)4096*HID;
        for (int kk = 0; kk <= SEQ; ++kk)
            k_scan<<<512, 256, 0, stream>>>(whh0, wih1, whh1, b0, b1, G0p,
                                            h0, c0, h1, c1, Y, kk);

        k_post<<<ROWS, 256, 0, stream>>>(Y, X, ln_g + blk*HID, ln_b + blk*HID, X);
    }

    // logits = x @ out_w^T + out_b in split-bf16 (~f32 accuracy; not amplified)
    k_cvt<<<1024, 256, 0, stream>>>(X, XHI, XLO, ROWS*HID);
    k_cvt<<<4096, 256, 0, stream>>>(out_w, OWHI, OWLO, VOCAB*HID);
    k_gemm3<<<16*250, 256, 0, stream>>>(XHI, XLO, OWHI, OWLO, logits, out_b,
                                        ROWS, VOCAB, HID);
}